// Round 8
// baseline (211.841 us; speedup 1.0000x reference)
//
#include <hip/hip_runtime.h>

// N=65536, E=1048576, nfeat=64, nhid=128. Inputs fp32; edge_index int32.
// Aggregation: LDS-staged edge binning into 512 buckets x 128 nodes, then
// per-bucket LDS-CSR + half-wave-paired register gather (no per-feature
// atomics). Gathers read bf16 x. GEMMs: bf16 MFMA 16x16x32, fp32 acc.
// BN folded into W2. Small prep work (casts, sigma, zeroing) fused in kprep.

#define BN_EPS 1e-5f
#define NB   512      // buckets (128 nodes each)
#define CAP  2816     // per-bucket capacity (avg 2048, +17 sigma; 16B-mult)

typedef float f4 __attribute__((ext_vector_type(4)));
typedef short bf8 __attribute__((ext_vector_type(8)));   // 8 bf16 = 4 VGPRs

__device__ inline short f2bf(float f) {
    unsigned u = __float_as_uint(f);
    u = u + 0x7fffu + ((u >> 16) & 1u);   // round-to-nearest-even
    return (short)(u >> 16);
}
__device__ inline float bf2f(unsigned short u) {
    return __uint_as_float((unsigned)u << 16);
}
__device__ inline unsigned pk2(float a, float b) {
    return (unsigned)(unsigned short)f2bf(a) |
           ((unsigned)(unsigned short)f2bf(b) << 16);
}
__device__ inline float wave_red_sum(float v) {
    v += __shfl_xor(v, 1);  v += __shfl_xor(v, 2);  v += __shfl_xor(v, 4);
    v += __shfl_xor(v, 8);  v += __shfl_xor(v, 16); v += __shfl_xor(v, 32);
    return v;
}

// ---------------- kprep: x->bf16, W1->bf16, zero counters, sigmas ----------------
// blocks 0..2047: x cast (each thread: 2 float4 -> 1 uint4)
// blocks 2048..2051: W1 cast (each thread: 8 elems)
// block 2052: zero gcount(512)+bnacc(256)
// block 2053: spectral-norm sigmas (parallelized)
__global__ __launch_bounds__(256) void kprep(const float* __restrict__ x,
                                             unsigned* __restrict__ xbf2,
                                             const float* __restrict__ W1,
                                             short* __restrict__ w1bf,
                                             const float* __restrict__ u1,
                                             const float* __restrict__ W2,
                                             const float* __restrict__ u2,
                                             float* __restrict__ sinv,
                                             int* __restrict__ zbase) {
    int bid = blockIdx.x;
    int t = threadIdx.x;
    if (bid < 2048) {
        int i = bid * 256 + t;               // uint4 index, N*8 total
        const float4* xp = (const float4*)x;
        float4 a = xp[2 * i], b = xp[2 * i + 1];
        uint4 o = {pk2(a.x, a.y), pk2(a.z, a.w), pk2(b.x, b.y), pk2(b.z, b.w)};
        ((uint4*)xbf2)[i] = o;
    } else if (bid < 2052) {
        int base = (bid - 2048) * 2048 + t * 8;   // 128*64 = 8192 elems
        float4 a = *(const float4*)(W1 + base);
        float4 b = *(const float4*)(W1 + base + 4);
        uint4 o = {pk2(a.x, a.y), pk2(a.z, a.w), pk2(b.x, b.y), pk2(b.z, b.w)};
        *(uint4*)(w1bf + base) = o;
    } else if (bid == 2052) {
        zbase[t] = 0; zbase[256 + t] = 0; zbase[512 + t] = 0;  // gcount+bnacc
    } else {
        // ---- sigmas ----
        __shared__ float red[256];
        __shared__ float vsh[128];
        __shared__ float res[128];
        // W1: v = (W1^T u1)/(||.||+1e-12)
        {
            int j = t & 63, q = t >> 6;
            float s = 0.f;
            for (int i = q * 32; i < q * 32 + 32; i++) s += W1[i * 64 + j] * u1[i];
            red[t] = s;
        }
        __syncthreads();
        if (t < 64) {
            float vj = red[t] + red[64 + t] + red[128 + t] + red[192 + t];
            float nv = sqrtf(wave_red_sum(vj * vj));
            vsh[t] = vj / (nv + 1e-12f);
        }
        __syncthreads();
        {
            int w = t >> 6, lane = t & 63;
            for (int row = w; row < 128; row += 4) {
                float p = W1[row * 64 + lane] * vsh[lane];
                p = wave_red_sum(p);
                if (lane == 0) res[row] = p;
            }
        }
        __syncthreads();
        if (t < 64) {
            float a = res[t] * res[t] + res[64 + t] * res[64 + t];
            float nt2 = wave_red_sum(a);
            if (t == 0) { float nt = sqrtf(nt2); sinv[0] = (nt + 1e-12f) / nt2; }
        }
        __syncthreads();
        // W2: v = (W2^T u2)/(||.||+1e-12)
        {
            int j = t & 127, h = t >> 7;
            float s = 0.f;
            for (int i = h * 64; i < h * 64 + 64; i++) s += W2[i * 128 + j] * u2[i];
            red[t] = s;
        }
        __syncthreads();
        if (t < 128) { float vj = red[t] + red[128 + t]; vsh[t] = vj; res[t] = vj * vj; }
        __syncthreads();
        if (t < 64) {
            float tot = wave_red_sum(res[t] + res[64 + t]);
            if (t == 0) res[0] = sqrtf(tot) + 1e-12f;
        }
        __syncthreads();
        if (t < 128) vsh[t] = vsh[t] / res[0];
        __syncthreads();
        {
            int w = t >> 6, lane = t & 63;
            for (int row = w; row < 128; row += 4) {
                float p = W2[row * 128 + lane] * vsh[lane]
                        + W2[row * 128 + 64 + lane] * vsh[64 + lane];
                p = wave_red_sum(p);
                if (lane == 0) res[row] = p;
            }
        }
        __syncthreads();
        if (t < 64) {
            float a = res[t] * res[t] + res[64 + t] * res[64 + t];
            float nt2 = wave_red_sum(a);
            if (t == 0) { float nt = sqrtf(nt2); sinv[1] = (nt + 1e-12f) / nt2; }
        }
    }
}

// ---------------- kbin: LDS-staged edge binning (512 buckets) ----------------
// 256 blocks x 512 threads, 4096 edges/block. Packed edge:
// [31:23]=bucket(9b), [22:7]=src(16b), [6:0]=dst&127.
__global__ __launch_bounds__(512) void kbin(const int* __restrict__ ei, int E,
                                            int* __restrict__ gcount,
                                            unsigned* __restrict__ pairs) {
    __shared__ int hist[512];
    __shared__ int sbase[512];
    __shared__ int cur[512];
    __shared__ int gofs[512];
    __shared__ unsigned stage[4096];
    int t = threadIdx.x;

    hist[t] = 0;
    __syncthreads();

    const uint4* s4 = (const uint4*)ei + blockIdx.x * 1024;
    const uint4* d4 = (const uint4*)(ei + E) + blockIdx.x * 1024;
    unsigned pk[8];
#pragma unroll
    for (int i = 0; i < 2; i++) {
        int idx = i * 512 + t;
        uint4 sv = s4[idx];
        uint4 dv = d4[idx];
        pk[i * 4 + 0] = ((dv.x >> 7) << 23) | (sv.x << 7) | (dv.x & 127u);
        pk[i * 4 + 1] = ((dv.y >> 7) << 23) | (sv.y << 7) | (dv.y & 127u);
        pk[i * 4 + 2] = ((dv.z >> 7) << 23) | (sv.z << 7) | (dv.z & 127u);
        pk[i * 4 + 3] = ((dv.w >> 7) << 23) | (sv.w << 7) | (dv.w & 127u);
        atomicAdd(&hist[dv.x >> 7], 1);
        atomicAdd(&hist[dv.y >> 7], 1);
        atomicAdd(&hist[dv.z >> 7], 1);
        atomicAdd(&hist[dv.w >> 7], 1);
    }
    __syncthreads();

    int cntb = hist[t];
    for (int o = 1; o < 512; o <<= 1) {
        int v = (t >= o) ? hist[t - o] : 0;
        __syncthreads();
        hist[t] += v;
        __syncthreads();
    }
    int excl = hist[t] - cntb;
    sbase[t] = excl;
    cur[t] = excl;
    __syncthreads();

#pragma unroll
    for (int i = 0; i < 8; i++) {
        int p = atomicAdd(&cur[pk[i] >> 23], 1);
        stage[p] = pk[i];
    }
    __syncthreads();

    gofs[t] = atomicAdd(&gcount[t], cntb);
    __syncthreads();

#pragma unroll
    for (int i = 0; i < 8; i++) {
        int p = i * 512 + t;
        unsigned v = stage[p];
        int b = (int)(v >> 23);
        int li = p - sbase[b];
        pairs[(size_t)b * CAP + gofs[b] + li] = v & 0x7FFFFFu;
    }
}

// ---------------- kaggs: per-bucket LDS-CSR + paired register gather ----------
// One 512-thread block per bucket (128 nodes). 2 blocks/CU. Local CSR in LDS
// (1 LDS atomic per edge), then wave-per-node accumulation: half-wave h
// handles edges of parity h; lane = feature-pair. __shfl_xor(32) combines.
__global__ __launch_bounds__(512) void kaggs(const unsigned* __restrict__ pairs,
                                             const int* __restrict__ gcount,
                                             const unsigned* __restrict__ xbf2,
                                             unsigned* __restrict__ hbf2) {
    __shared__ unsigned ep[CAP];            // staged pairs (11 KB)
    __shared__ unsigned short sorted[CAP];  // src16 grouped by local dst (5.5 KB)
    __shared__ int hist[128];               // inclusive scan (end offsets)
    __shared__ int offs[128];               // exclusive scan (begin offsets)
    __shared__ int cur[128];
    int t = threadIdx.x;
    int b = blockIdx.x;
    int cnt = gcount[b];

    {
        const uint4* gp4 = (const uint4*)(pairs + (size_t)b * CAP);
        int cnt4 = (cnt + 3) >> 2;
        for (int j = t; j < cnt4; j += 512) ((uint4*)ep)[j] = gp4[j];
    }
    if (t < 128) hist[t] = 0;
    __syncthreads();
    for (int j = t; j < cnt; j += 512) atomicAdd(&hist[ep[j] & 127u], 1);
    __syncthreads();
    int cntb = (t < 128) ? hist[t] : 0;
    for (int o = 1; o < 128; o <<= 1) {
        int v = (t < 128 && t >= o) ? hist[t - o] : 0;
        __syncthreads();
        if (t < 128) hist[t] += v;
        __syncthreads();
    }
    if (t < 128) { offs[t] = hist[t] - cntb; cur[t] = hist[t] - cntb; }
    __syncthreads();
    for (int j = t; j < cnt; j += 512) {
        unsigned v = ep[j];
        int p = atomicAdd(&cur[v & 127u], 1);
        sorted[p] = (unsigned short)(v >> 7);
    }
    __syncthreads();

    int w = t >> 6;
    int lane = t & 63;
    int h = lane >> 5;        // half-wave: edge parity
    int l = lane & 31;        // feature-pair index (features 2l, 2l+1)

#pragma unroll
    for (int ni = 0; ni < 16; ni++) {
        int n = w * 16 + ni;                 // local node (8 waves x 16 = 128)
        int g = b * 128 + n;                 // global node
        int beg = offs[n], end = hist[n];
        float a0 = 0.f, a1 = 0.f, b0 = 0.f, b1 = 0.f;
        float c0 = 0.f, c1 = 0.f, d0 = 0.f, d1 = 0.f;
        int j = beg + h;
        for (; j + 6 < end; j += 8) {
            int s0 = sorted[j];
            int s1 = sorted[j + 2];
            int s2 = sorted[j + 4];
            int s3 = sorted[j + 6];
            unsigned v0 = xbf2[(size_t)s0 * 32 + l];
            unsigned v1 = xbf2[(size_t)s1 * 32 + l];
            unsigned v2 = xbf2[(size_t)s2 * 32 + l];
            unsigned v3 = xbf2[(size_t)s3 * 32 + l];
            a0 += bf2f((unsigned short)v0); a1 += bf2f((unsigned short)(v0 >> 16));
            b0 += bf2f((unsigned short)v1); b1 += bf2f((unsigned short)(v1 >> 16));
            c0 += bf2f((unsigned short)v2); c1 += bf2f((unsigned short)(v2 >> 16));
            d0 += bf2f((unsigned short)v3); d1 += bf2f((unsigned short)(v3 >> 16));
        }
        for (; j < end; j += 2) {
            unsigned v = xbf2[(size_t)sorted[j] * 32 + l];
            a0 += bf2f((unsigned short)v); a1 += bf2f((unsigned short)(v >> 16));
        }
        a0 = (a0 + b0) + (c0 + d0);
        a1 = (a1 + b1) + (c1 + d1);
        a0 += __shfl_xor(a0, 32);
        a1 += __shfl_xor(a1, 32);
        unsigned xs = xbf2[(size_t)g * 32 + l];
        a0 += bf2f((unsigned short)xs);
        a1 += bf2f((unsigned short)(xs >> 16));
        if (h == 0) hbf2[(size_t)g * 32 + l] = pk2(a0, a1);
    }
}

// ---------------- K3: h1 = relu(s1*(h @ W1^T) + b1) via MFMA + BN atomics ----
__global__ __launch_bounds__(256) void k3_gemm1(const short* __restrict__ hbf,
                                                const short* __restrict__ w1bf,
                                                const float* __restrict__ b1,
                                                const float* __restrict__ sinv,
                                                short* __restrict__ h1bf,
                                                float* __restrict__ bnacc) {
    __shared__ short u[16384];          // 32 KB
    __shared__ float red1[512], red2[512];
    int t = threadIdx.x;
    int n0 = blockIdx.x * 128;

    const bf8* hsrc = (const bf8*)(hbf + (size_t)n0 * 64);
    const bf8* wsrc = (const bf8*)w1bf;
#pragma unroll
    for (int i = 0; i < 4; i++) {
        int idx = i * 256 + t;
        int row = idx >> 3, c = idx & 7;
        int cs = c ^ (row & 7);
        *(bf8*)&u[row * 64 + cs * 8] = hsrc[idx];
    }
#pragma unroll
    for (int i = 0; i < 4; i++) {
        int idx = i * 256 + t;
        int row = idx >> 3, c = idx & 7;
        int cs = c ^ (row & 7);
        *(bf8*)&u[8192 + row * 64 + cs * 8] = wsrc[idx];
    }
    __syncthreads();

    int w = t >> 6;
    int l15 = t & 15, quad = (t & 63) >> 4;

    f4 acc[2][8];
#pragma unroll
    for (int mt = 0; mt < 2; mt++)
#pragma unroll
        for (int nt = 0; nt < 8; nt++) acc[mt][nt] = (f4){0.f, 0.f, 0.f, 0.f};

#pragma unroll
    for (int ks = 0; ks < 2; ks++) {
        bf8 a[2], b[8];
#pragma unroll
        for (int mt = 0; mt < 2; mt++) {
            int node = w * 32 + mt * 16 + l15;
            int cs = (ks * 4 + quad) ^ (node & 7);
            a[mt] = *(const bf8*)&u[node * 64 + cs * 8];
        }
#pragma unroll
        for (int nt = 0; nt < 8; nt++) {
            int o = nt * 16 + l15;
            int cs = (ks * 4 + quad) ^ (o & 7);
            b[nt] = *(const bf8*)&u[8192 + o * 64 + cs * 8];
        }
#pragma unroll
        for (int mt = 0; mt < 2; mt++)
#pragma unroll
            for (int nt = 0; nt < 8; nt++)
                acc[mt][nt] = __builtin_amdgcn_mfma_f32_16x16x32_bf16(
                    a[mt], b[nt], acc[mt][nt], 0, 0, 0);
    }

    float s1 = sinv[0];
    float b1v[8];
#pragma unroll
    for (int nt = 0; nt < 8; nt++) b1v[nt] = b1[nt * 16 + l15];

#pragma unroll
    for (int nt = 0; nt < 8; nt++) {
        float s = 0.f, q = 0.f;
#pragma unroll
        for (int mt = 0; mt < 2; mt++)
#pragma unroll
            for (int r = 0; r < 4; r++) {
                float v = fmaxf(fmaf(acc[mt][nt][r], s1, b1v[nt]), 0.f);
                acc[mt][nt][r] = v;
                s += v; q += v * v;
            }
        s += __shfl_xor(s, 16); s += __shfl_xor(s, 32);
        q += __shfl_xor(q, 16); q += __shfl_xor(q, 32);
        if (quad == 0) {
            red1[w * 128 + nt * 16 + l15] = s;
            red2[w * 128 + nt * 16 + l15] = q;
        }
    }
    __syncthreads();

#pragma unroll
    for (int mt = 0; mt < 2; mt++)
#pragma unroll
        for (int nt = 0; nt < 8; nt++) {
            int col = nt * 16 + l15;
#pragma unroll
            for (int r = 0; r < 4; r++) {
                int node = w * 32 + mt * 16 + quad * 4 + r;
                int cs = (col >> 3) ^ (node & 15);
                u[node * 128 + cs * 8 + (col & 7)] = f2bf(acc[mt][nt][r]);
            }
        }
    __syncthreads();

    short* dst = h1bf + (size_t)n0 * 128;
#pragma unroll
    for (int i = 0; i < 8; i++) {
        int idx = i * 256 + t;
        int row = idx >> 4, c = idx & 15;
        int cs = c ^ (row & 15);
        *(bf8*)&dst[idx * 8] = *(const bf8*)&u[row * 128 + cs * 8];
    }
    if (t < 128) {
        float s = red1[t] + red1[128 + t] + red1[256 + t] + red1[384 + t];
        float q = red2[t] + red2[128 + t] + red2[256 + t] + red2[384 + t];
        atomicAdd(&bnacc[t], s);
        atomicAdd(&bnacc[128 + t], q);
    }
}

// ---------------- K4: fold BN + sigma2 into W2f(bf16), b2f(fp32) ----------------
__global__ __launch_bounds__(128) void k4_fold(const float* __restrict__ bnacc,
                                               int N,
                                               const float* __restrict__ gamma,
                                               const float* __restrict__ beta,
                                               const float* __restrict__ W2,
                                               const float* __restrict__ b2,
                                               const float* __restrict__ sinv,
                                               short* __restrict__ W2fbf,
                                               float* __restrict__ b2f) {
    __shared__ float a_s[128], c_s[128];
    int t = threadIdx.x;
    {
        float mean = bnacc[t] / (float)N;
        float var = bnacc[t + 128] / (float)N - mean * mean;
        float rstd = rsqrtf(var + BN_EPS);
        float a = rstd * gamma[t];
        a_s[t] = a;
        c_s[t] = beta[t] - mean * a;
    }
    __syncthreads();
    float s2 = sinv[1];
    float accb = 0.f;
    for (int j = 0; j < 128; j++) {
        float w = W2[t * 128 + j] * s2;
        W2fbf[t * 128 + j] = f2bf(w * a_s[j]);
        accb += w * c_s[j];
    }
    b2f[t] = b2[t] + accb;
}

// ---------------- K5: out = h1 @ W2f^T + b2f via MFMA ----------------
__global__ __launch_bounds__(256) void k5_gemm2(const short* __restrict__ h1bf,
                                                const short* __restrict__ w2fbf,
                                                const float* __restrict__ b2f,
                                                float* __restrict__ out) {
    __shared__ short s5[32768];
    int t = threadIdx.x;
    int n0 = blockIdx.x * 128;

    const bf8* hsrc = (const bf8*)(h1bf + (size_t)n0 * 128);
    const bf8* wsrc = (const bf8*)w2fbf;
#pragma unroll
    for (int i = 0; i < 8; i++) {
        int idx = i * 256 + t;
        int row = idx >> 4, c = idx & 15;
        int cs = c ^ (row & 15);
        *(bf8*)&s5[row * 128 + cs * 8] = hsrc[idx];
    }
#pragma unroll
    for (int i = 0; i < 8; i++) {
        int idx = i * 256 + t;
        int row = idx >> 4, c = idx & 15;
        int cs = c ^ (row & 15);
        *(bf8*)&s5[16384 + row * 128 + cs * 8] = wsrc[idx];
    }
    __syncthreads();

    int w = t >> 6;
    int l15 = t & 15, quad = (t & 63) >> 4;

    f4 acc[2][8];
#pragma unroll
    for (int mt = 0; mt < 2; mt++)
#pragma unroll
        for (int nt = 0; nt < 8; nt++) acc[mt][nt] = (f4){0.f, 0.f, 0.f, 0.f};

#pragma unroll
    for (int ks = 0; ks < 4; ks++) {
        bf8 a[2], b[8];
#pragma unroll
        for (int mt = 0; mt < 2; mt++) {
            int node = w * 32 + mt * 16 + l15;
            int cs = (ks * 4 + quad) ^ (node & 15);
            a[mt] = *(const bf8*)&s5[node * 128 + cs * 8];
        }
#pragma unroll
        for (int nt = 0; nt < 8; nt++) {
            int o = nt * 16 + l15;
            int cs = (ks * 4 + quad) ^ (o & 15);
            b[nt] = *(const bf8*)&s5[16384 + o * 128 + cs * 8];
        }
#pragma unroll
        for (int mt = 0; mt < 2; mt++)
#pragma unroll
            for (int nt = 0; nt < 8; nt++)
                acc[mt][nt] = __builtin_amdgcn_mfma_f32_16x16x32_bf16(
                    a[mt], b[nt], acc[mt][nt], 0, 0, 0);
    }

    float b2v[8];
#pragma unroll
    for (int nt = 0; nt < 8; nt++) b2v[nt] = b2f[nt * 16 + l15];

#pragma unroll
    for (int mt = 0; mt < 2; mt++)
#pragma unroll
        for (int nt = 0; nt < 8; nt++)
#pragma unroll
            for (int r = 0; r < 4; r++) {
                int node = n0 + w * 32 + mt * 16 + quad * 4 + r;
                out[(size_t)node * 128 + nt * 16 + l15] = acc[mt][nt][r] + b2v[nt];
            }
}

extern "C" void kernel_launch(void* const* d_in, const int* in_sizes, int n_in,
                              void* d_out, int out_size, void* d_ws, size_t ws_size,
                              hipStream_t stream) {
    const float* x     = (const float*)d_in[0];
    const int*   ei    = (const int*)d_in[1];
    const float* W1    = (const float*)d_in[2];
    const float* b1    = (const float*)d_in[3];
    const float* u1    = (const float*)d_in[4];
    const float* gamma = (const float*)d_in[5];
    const float* beta  = (const float*)d_in[6];
    const float* W2    = (const float*)d_in[7];
    const float* b2    = (const float*)d_in[8];
    const float* u2    = (const float*)d_in[9];
    float* out = (float*)d_out;

    int N = in_sizes[0] / 64;     // 65536
    int E = in_sizes[1] / 2;      // 1048576
    int nblk = N / 128;           // 512

    char* ws = (char*)d_ws;
    size_t off = 0;
    short* hbf     = (short*)(ws + off); off += (size_t)N * 64 * 2;      // 8 MB
    char*  region2 = ws + off;           off += (size_t)N * 128 * 2;     // 16 MB
    // region2 lifetime: [pairs 5.77MB | xbf 8MB] die after kaggs; then h1bf.
    unsigned* pairs = (unsigned*)region2;
    unsigned short* xbf = (unsigned short*)(region2 + (size_t)NB * CAP * 4);
    short*    h1bf  = (short*)region2;
    int*   gcount  = (int*)(ws + off);   off += 512 * 4;
    float* bnacc   = (float*)(ws + off); off += 256 * 4;   // contiguous w/ gcount
    float* sinv    = (float*)(ws + off); off += 16 * 4;
    float* b2f     = (float*)(ws + off); off += 128 * 4;
    short* w1bf    = (short*)(ws + off); off += 128 * 64 * 2;
    short* w2fbf   = (short*)(ws + off); off += 128 * 128 * 2;

    // prep: x->bf16, W1->bf16, zero gcount+bnacc, sigmas  (2054 blocks)
    kprep<<<2054, 256, 0, stream>>>(x, (unsigned*)xbf, W1, w1bf, u1, W2, u2,
                                    sinv, gcount);
    // bin edges into 512 per-bucket packed lists (contiguous flushes)
    kbin<<<E / 4096, 512, 0, stream>>>(ei, E, gcount, pairs);
    // per-bucket LDS-CSR + paired register gather: hbf = bf16(x + sum x[src])
    kaggs<<<NB, 512, 0, stream>>>(pairs, gcount, (const unsigned*)xbf,
                                  (unsigned*)hbf);
    // h1 = relu(gemm1) -> bf16 + BN atomic accumulation
    k3_gemm1<<<nblk, 256, 0, stream>>>(hbf, w1bf, b1, sinv, h1bf, bnacc);
    // fold BN + sigma2 into bf16 W2f
    k4_fold<<<1, 128, 0, stream>>>(bnacc, N, gamma, beta, W2, b2, sinv, w2fbf, b2f);
    // out = h1 @ W2f^T + b2f
    k5_gemm2<<<nblk, 256, 0, stream>>>(h1bf, w2fbf, b2f, out);
}

// Round 9
// 179.762 us; speedup vs baseline: 1.1785x; 1.1785x over previous
//
#include <hip/hip_runtime.h>

// N=65536, E=1048576, nfeat=64, nhid=128. Inputs fp32; edge_index int32.
// Aggregation: LDS-staged edge binning into 512 buckets x 128 nodes, then
// per-bucket LDS-CSR + half-wave-paired register gather (no per-feature
// atomics). Gathers read bf16 x. GEMMs: bf16 MFMA 16x16x32, fp32 acc.
// BN folded into W2. Sigma computed in a spare block of kbin (hidden).

#define BN_EPS 1e-5f
#define NB   512      // buckets (128 nodes each)
#define CAP  2816     // per-bucket capacity (avg 2048, +17 sigma; 16B-mult)

typedef float f4 __attribute__((ext_vector_type(4)));
typedef short bf8 __attribute__((ext_vector_type(8)));   // 8 bf16 = 4 VGPRs

__device__ inline short f2bf(float f) {
    unsigned u = __float_as_uint(f);
    u = u + 0x7fffu + ((u >> 16) & 1u);   // round-to-nearest-even
    return (short)(u >> 16);
}
__device__ inline float bf2f(unsigned short u) {
    return __uint_as_float((unsigned)u << 16);
}
__device__ inline unsigned pk2(float a, float b) {
    return (unsigned)(unsigned short)f2bf(a) |
           ((unsigned)(unsigned short)f2bf(b) << 16);
}

// ---------------- kprep: x->bf16, W1->bf16, zero counters ----------------
// blocks 0..2047: x cast (each thread: 2 float4 -> 1 uint4)
// blocks 2048..2051: W1 cast; block 2052: zero gcount(512)+bnacc(256)
__global__ __launch_bounds__(256) void kprep(const float* __restrict__ x,
                                             unsigned* __restrict__ xbf2,
                                             const float* __restrict__ W1,
                                             short* __restrict__ w1bf,
                                             int* __restrict__ zbase) {
    int bid = blockIdx.x;
    int t = threadIdx.x;
    if (bid < 2048) {
        int i = bid * 256 + t;               // uint4 index, N*8 total
        const float4* xp = (const float4*)x;
        float4 a = xp[2 * i], b = xp[2 * i + 1];
        uint4 o = {pk2(a.x, a.y), pk2(a.z, a.w), pk2(b.x, b.y), pk2(b.z, b.w)};
        ((uint4*)xbf2)[i] = o;
    } else if (bid < 2052) {
        int base = (bid - 2048) * 2048 + t * 8;   // 128*64 = 8192 elems
        float4 a = *(const float4*)(W1 + base);
        float4 b = *(const float4*)(W1 + base + 4);
        uint4 o = {pk2(a.x, a.y), pk2(a.z, a.w), pk2(b.x, b.y), pk2(b.z, b.w)};
        *(uint4*)(w1bf + base) = o;
    } else {
        zbase[t] = 0; zbase[256 + t] = 0; zbase[512 + t] = 0;  // gcount+bnacc
    }
}

// ---------------- kbin: LDS-staged edge binning (512 buckets) + sigma ----------
// Blocks 0..255: binning, 4096 edges/block. Packed edge:
// [31:23]=bucket(9b), [22:7]=src(16b), [6:0]=dst&127.
// Block 256: spectral-norm sigmas (LDS-tree reductions, float4 row dots).
__global__ __launch_bounds__(512) void kbin(const int* __restrict__ ei, int E,
                                            int* __restrict__ gcount,
                                            unsigned* __restrict__ pairs,
                                            const float* __restrict__ W1,
                                            const float* __restrict__ u1,
                                            const float* __restrict__ W2,
                                            const float* __restrict__ u2,
                                            float* __restrict__ sinv) {
    __shared__ int hist[512];
    __shared__ int sbase[512];
    __shared__ int cur[512];
    __shared__ int gofs[512];
    __shared__ unsigned stage[4096];
    int t = threadIdx.x;

    if (blockIdx.x < 256) {
        hist[t] = 0;
        __syncthreads();

        const uint4* s4 = (const uint4*)ei + blockIdx.x * 1024;
        const uint4* d4 = (const uint4*)(ei + E) + blockIdx.x * 1024;
        unsigned pk[8];
#pragma unroll
        for (int i = 0; i < 2; i++) {
            int idx = i * 512 + t;
            uint4 sv = s4[idx];
            uint4 dv = d4[idx];
            pk[i * 4 + 0] = ((dv.x >> 7) << 23) | (sv.x << 7) | (dv.x & 127u);
            pk[i * 4 + 1] = ((dv.y >> 7) << 23) | (sv.y << 7) | (dv.y & 127u);
            pk[i * 4 + 2] = ((dv.z >> 7) << 23) | (sv.z << 7) | (dv.z & 127u);
            pk[i * 4 + 3] = ((dv.w >> 7) << 23) | (sv.w << 7) | (dv.w & 127u);
            atomicAdd(&hist[dv.x >> 7], 1);
            atomicAdd(&hist[dv.y >> 7], 1);
            atomicAdd(&hist[dv.z >> 7], 1);
            atomicAdd(&hist[dv.w >> 7], 1);
        }
        __syncthreads();

        int cntb = hist[t];
        for (int o = 1; o < 512; o <<= 1) {
            int v = (t >= o) ? hist[t - o] : 0;
            __syncthreads();
            hist[t] += v;
            __syncthreads();
        }
        int excl = hist[t] - cntb;
        sbase[t] = excl;
        cur[t] = excl;
        __syncthreads();

#pragma unroll
        for (int i = 0; i < 8; i++) {
            int p = atomicAdd(&cur[pk[i] >> 23], 1);
            stage[p] = pk[i];
        }
        __syncthreads();

        gofs[t] = atomicAdd(&gcount[t], cntb);
        __syncthreads();

#pragma unroll
        for (int i = 0; i < 8; i++) {
            int p = i * 512 + t;
            unsigned v = stage[p];
            int b = (int)(v >> 23);
            int li = p - sbase[b];
            pairs[(size_t)b * CAP + gofs[b] + li] = v & 0x7FFFFFu;
        }
    } else {
        // ---- sigma block: alias LDS ----
        float* red = (float*)stage;     // 512 floats
        float* v   = (float*)hist;      // 128 floats
        float* sq  = (float*)sbase;     // 512 floats scratch

        // === W1 (128x64) ===
        {   // v_j = sum_i W1[i,j] * u1[i] : 8 groups of 16 rows
            int j = t & 63, q = t >> 6;
            float s = 0.f;
            for (int i = q * 16; i < q * 16 + 16; i++) s += W1[i * 64 + j] * u1[i];
            red[t] = s;
        }
        __syncthreads();
        if (t < 64) {
            float vj = 0.f;
#pragma unroll
            for (int g = 0; g < 8; g++) vj += red[g * 64 + t];
            v[t] = vj; sq[t] = vj * vj;
        }
        __syncthreads();
        for (int s2 = 32; s2 > 0; s2 >>= 1) {
            if (t < s2) sq[t] += sq[t + s2];
            __syncthreads();
        }
        if (t < 64) v[t] = v[t] / (sqrtf(sq[0]) + 1e-12f);
        __syncthreads();
        {   // t_r = W1[r,:]·v : 4 threads/row, float4 dots
            int r = t >> 2, h = t & 3;
            const float4* wr = (const float4*)(W1 + r * 64 + h * 16);
            const float4* vv = (const float4*)v + h * 4;
            float s = 0.f;
#pragma unroll
            for (int k = 0; k < 4; k++) {
                float4 a = wr[k]; float4 b = vv[k];
                s += a.x * b.x + a.y * b.y + a.z * b.z + a.w * b.w;
            }
            red[t] = s;
        }
        __syncthreads();
        if (t < 128) {
            float tr = (red[4 * t] + red[4 * t + 1]) + (red[4 * t + 2] + red[4 * t + 3]);
            sq[t] = tr * tr;
        }
        __syncthreads();
        for (int s2 = 64; s2 > 0; s2 >>= 1) {
            if (t < s2) sq[t] += sq[t + s2];
            __syncthreads();
        }
        if (t == 0) { float nt2 = sq[0]; sinv[0] = (sqrtf(nt2) + 1e-12f) / nt2; }
        __syncthreads();

        // === W2 (128x128) ===
        {   // v_j = sum_i W2[i,j] * u2[i] : 4 groups of 32 rows
            int j = t & 127, q = t >> 7;
            float s = 0.f;
            for (int i = q * 32; i < q * 32 + 32; i++) s += W2[i * 128 + j] * u2[i];
            red[t] = s;
        }
        __syncthreads();
        if (t < 128) {
            float vj = (red[t] + red[128 + t]) + (red[256 + t] + red[384 + t]);
            v[t] = vj; sq[t] = vj * vj;
        }
        __syncthreads();
        for (int s2 = 64; s2 > 0; s2 >>= 1) {
            if (t < s2) sq[t] += sq[t + s2];
            __syncthreads();
        }
        if (t < 128) v[t] = v[t] / (sqrtf(sq[0]) + 1e-12f);
        __syncthreads();
        {   // t_r = W2[r,:]·v : 4 threads/row, 8 float4 dots
            int r = t >> 2, h = t & 3;
            const float4* wr = (const float4*)(W2 + r * 128 + h * 32);
            const float4* vv = (const float4*)v + h * 8;
            float s = 0.f;
#pragma unroll
            for (int k = 0; k < 8; k++) {
                float4 a = wr[k]; float4 b = vv[k];
                s += a.x * b.x + a.y * b.y + a.z * b.z + a.w * b.w;
            }
            red[t] = s;
        }
        __syncthreads();
        if (t < 128) {
            float tr = (red[4 * t] + red[4 * t + 1]) + (red[4 * t + 2] + red[4 * t + 3]);
            sq[t] = tr * tr;
        }
        __syncthreads();
        for (int s2 = 64; s2 > 0; s2 >>= 1) {
            if (t < s2) sq[t] += sq[t + s2];
            __syncthreads();
        }
        if (t == 0) { float nt2 = sq[0]; sinv[1] = (sqrtf(nt2) + 1e-12f) / nt2; }
    }
}

// ---------------- kaggs: per-bucket LDS-CSR + paired register gather ----------
// One 512-thread block per bucket (128 nodes). Local CSR in LDS (1 LDS atomic
// per edge), then wave-per-node accumulation: half-wave h handles edges of
// parity h; lane = feature-pair. __shfl_xor(32) combines.
__global__ __launch_bounds__(512) void kaggs(const unsigned* __restrict__ pairs,
                                             const int* __restrict__ gcount,
                                             const unsigned* __restrict__ xbf2,
                                             unsigned* __restrict__ hbf2) {
    __shared__ unsigned ep[CAP];            // staged pairs (11 KB)
    __shared__ unsigned short sorted[CAP];  // src16 grouped by local dst (5.5 KB)
    __shared__ int hist[128];               // inclusive scan (end offsets)
    __shared__ int offs[128];               // exclusive scan (begin offsets)
    __shared__ int cur[128];
    int t = threadIdx.x;
    int b = blockIdx.x;
    int cnt = gcount[b];

    {
        const uint4* gp4 = (const uint4*)(pairs + (size_t)b * CAP);
        int cnt4 = (cnt + 3) >> 2;
        for (int j = t; j < cnt4; j += 512) ((uint4*)ep)[j] = gp4[j];
    }
    if (t < 128) hist[t] = 0;
    __syncthreads();
    for (int j = t; j < cnt; j += 512) atomicAdd(&hist[ep[j] & 127u], 1);
    __syncthreads();
    int cntb = (t < 128) ? hist[t] : 0;
    for (int o = 1; o < 128; o <<= 1) {
        int v = (t < 128 && t >= o) ? hist[t - o] : 0;
        __syncthreads();
        if (t < 128) hist[t] += v;
        __syncthreads();
    }
    if (t < 128) { offs[t] = hist[t] - cntb; cur[t] = hist[t] - cntb; }
    __syncthreads();
    for (int j = t; j < cnt; j += 512) {
        unsigned v = ep[j];
        int p = atomicAdd(&cur[v & 127u], 1);
        sorted[p] = (unsigned short)(v >> 7);
    }
    __syncthreads();

    int w = t >> 6;
    int lane = t & 63;
    int h = lane >> 5;        // half-wave: edge parity
    int l = lane & 31;        // feature-pair index (features 2l, 2l+1)

#pragma unroll
    for (int ni = 0; ni < 16; ni++) {
        int n = w * 16 + ni;                 // local node (8 waves x 16 = 128)
        int g = b * 128 + n;                 // global node
        int beg = offs[n], end = hist[n];
        float a0 = 0.f, a1 = 0.f, b0 = 0.f, b1 = 0.f;
        float c0 = 0.f, c1 = 0.f, d0 = 0.f, d1 = 0.f;
        int j = beg + h;
        for (; j + 6 < end; j += 8) {
            int s0 = sorted[j];
            int s1 = sorted[j + 2];
            int s2 = sorted[j + 4];
            int s3 = sorted[j + 6];
            unsigned v0 = xbf2[(size_t)s0 * 32 + l];
            unsigned v1 = xbf2[(size_t)s1 * 32 + l];
            unsigned v2 = xbf2[(size_t)s2 * 32 + l];
            unsigned v3 = xbf2[(size_t)s3 * 32 + l];
            a0 += bf2f((unsigned short)v0); a1 += bf2f((unsigned short)(v0 >> 16));
            b0 += bf2f((unsigned short)v1); b1 += bf2f((unsigned short)(v1 >> 16));
            c0 += bf2f((unsigned short)v2); c1 += bf2f((unsigned short)(v2 >> 16));
            d0 += bf2f((unsigned short)v3); d1 += bf2f((unsigned short)(v3 >> 16));
        }
        for (; j < end; j += 2) {
            unsigned v = xbf2[(size_t)sorted[j] * 32 + l];
            a0 += bf2f((unsigned short)v); a1 += bf2f((unsigned short)(v >> 16));
        }
        a0 = (a0 + b0) + (c0 + d0);
        a1 = (a1 + b1) + (c1 + d1);
        a0 += __shfl_xor(a0, 32);
        a1 += __shfl_xor(a1, 32);
        unsigned xs = xbf2[(size_t)g * 32 + l];
        a0 += bf2f((unsigned short)xs);
        a1 += bf2f((unsigned short)(xs >> 16));
        if (h == 0) hbf2[(size_t)g * 32 + l] = pk2(a0, a1);
    }
}

// ---------------- K3: h1 = relu(s1*(h @ W1^T) + b1) via MFMA + BN atomics ----
__global__ __launch_bounds__(256) void k3_gemm1(const short* __restrict__ hbf,
                                                const short* __restrict__ w1bf,
                                                const float* __restrict__ b1,
                                                const float* __restrict__ sinv,
                                                short* __restrict__ h1bf,
                                                float* __restrict__ bnacc) {
    __shared__ short u[16384];          // 32 KB
    __shared__ float red1[512], red2[512];
    int t = threadIdx.x;
    int n0 = blockIdx.x * 128;

    const bf8* hsrc = (const bf8*)(hbf + (size_t)n0 * 64);
    const bf8* wsrc = (const bf8*)w1bf;
#pragma unroll
    for (int i = 0; i < 4; i++) {
        int idx = i * 256 + t;
        int row = idx >> 3, c = idx & 7;
        int cs = c ^ (row & 7);
        *(bf8*)&u[row * 64 + cs * 8] = hsrc[idx];
    }
#pragma unroll
    for (int i = 0; i < 4; i++) {
        int idx = i * 256 + t;
        int row = idx >> 3, c = idx & 7;
        int cs = c ^ (row & 7);
        *(bf8*)&u[8192 + row * 64 + cs * 8] = wsrc[idx];
    }
    __syncthreads();

    int w = t >> 6;
    int l15 = t & 15, quad = (t & 63) >> 4;

    f4 acc[2][8];
#pragma unroll
    for (int mt = 0; mt < 2; mt++)
#pragma unroll
        for (int nt = 0; nt < 8; nt++) acc[mt][nt] = (f4){0.f, 0.f, 0.f, 0.f};

#pragma unroll
    for (int ks = 0; ks < 2; ks++) {
        bf8 a[2], b[8];
#pragma unroll
        for (int mt = 0; mt < 2; mt++) {
            int node = w * 32 + mt * 16 + l15;
            int cs = (ks * 4 + quad) ^ (node & 7);
            a[mt] = *(const bf8*)&u[node * 64 + cs * 8];
        }
#pragma unroll
        for (int nt = 0; nt < 8; nt++) {
            int o = nt * 16 + l15;
            int cs = (ks * 4 + quad) ^ (o & 7);
            b[nt] = *(const bf8*)&u[8192 + o * 64 + cs * 8];
        }
#pragma unroll
        for (int mt = 0; mt < 2; mt++)
#pragma unroll
            for (int nt = 0; nt < 8; nt++)
                acc[mt][nt] = __builtin_amdgcn_mfma_f32_16x16x32_bf16(
                    a[mt], b[nt], acc[mt][nt], 0, 0, 0);
    }

    float s1 = sinv[0];
    float b1v[8];
#pragma unroll
    for (int nt = 0; nt < 8; nt++) b1v[nt] = b1[nt * 16 + l15];

#pragma unroll
    for (int nt = 0; nt < 8; nt++) {
        float s = 0.f, q = 0.f;
#pragma unroll
        for (int mt = 0; mt < 2; mt++)
#pragma unroll
            for (int r = 0; r < 4; r++) {
                float v = fmaxf(fmaf(acc[mt][nt][r], s1, b1v[nt]), 0.f);
                acc[mt][nt][r] = v;
                s += v; q += v * v;
            }
        s += __shfl_xor(s, 16); s += __shfl_xor(s, 32);
        q += __shfl_xor(q, 16); q += __shfl_xor(q, 32);
        if (quad == 0) {
            red1[w * 128 + nt * 16 + l15] = s;
            red2[w * 128 + nt * 16 + l15] = q;
        }
    }
    __syncthreads();

#pragma unroll
    for (int mt = 0; mt < 2; mt++)
#pragma unroll
        for (int nt = 0; nt < 8; nt++) {
            int col = nt * 16 + l15;
#pragma unroll
            for (int r = 0; r < 4; r++) {
                int node = w * 32 + mt * 16 + quad * 4 + r;
                int cs = (col >> 3) ^ (node & 15);
                u[node * 128 + cs * 8 + (col & 7)] = f2bf(acc[mt][nt][r]);
            }
        }
    __syncthreads();

    short* dst = h1bf + (size_t)n0 * 128;
#pragma unroll
    for (int i = 0; i < 8; i++) {
        int idx = i * 256 + t;
        int row = idx >> 4, c = idx & 15;
        int cs = c ^ (row & 15);
        *(bf8*)&dst[idx * 8] = *(const bf8*)&u[row * 128 + cs * 8];
    }
    if (t < 128) {
        float s = red1[t] + red1[128 + t] + red1[256 + t] + red1[384 + t];
        float q = red2[t] + red2[128 + t] + red2[256 + t] + red2[384 + t];
        atomicAdd(&bnacc[t], s);
        atomicAdd(&bnacc[128 + t], q);
    }
}

// ---------------- K4: fold BN + sigma2 into W2f(bf16), b2f(fp32) ----------------
__global__ __launch_bounds__(128) void k4_fold(const float* __restrict__ bnacc,
                                               int N,
                                               const float* __restrict__ gamma,
                                               const float* __restrict__ beta,
                                               const float* __restrict__ W2,
                                               const float* __restrict__ b2,
                                               const float* __restrict__ sinv,
                                               short* __restrict__ W2fbf,
                                               float* __restrict__ b2f) {
    __shared__ float a_s[128], c_s[128];
    int t = threadIdx.x;
    {
        float mean = bnacc[t] / (float)N;
        float var = bnacc[t + 128] / (float)N - mean * mean;
        float rstd = rsqrtf(var + BN_EPS);
        float a = rstd * gamma[t];
        a_s[t] = a;
        c_s[t] = beta[t] - mean * a;
    }
    __syncthreads();
    float s2 = sinv[1];
    float accb = 0.f;
    for (int j = 0; j < 128; j++) {
        float w = W2[t * 128 + j] * s2;
        W2fbf[t * 128 + j] = f2bf(w * a_s[j]);
        accb += w * c_s[j];
    }
    b2f[t] = b2[t] + accb;
}

// ---------------- K5: out = h1 @ W2f^T + b2f via MFMA ----------------
__global__ __launch_bounds__(256) void k5_gemm2(const short* __restrict__ h1bf,
                                                const short* __restrict__ w2fbf,
                                                const float* __restrict__ b2f,
                                                float* __restrict__ out) {
    __shared__ short s5[32768];
    int t = threadIdx.x;
    int n0 = blockIdx.x * 128;

    const bf8* hsrc = (const bf8*)(h1bf + (size_t)n0 * 128);
    const bf8* wsrc = (const bf8*)w2fbf;
#pragma unroll
    for (int i = 0; i < 8; i++) {
        int idx = i * 256 + t;
        int row = idx >> 4, c = idx & 15;
        int cs = c ^ (row & 15);
        *(bf8*)&s5[row * 128 + cs * 8] = hsrc[idx];
    }
#pragma unroll
    for (int i = 0; i < 8; i++) {
        int idx = i * 256 + t;
        int row = idx >> 4, c = idx & 15;
        int cs = c ^ (row & 15);
        *(bf8*)&s5[16384 + row * 128 + cs * 8] = wsrc[idx];
    }
    __syncthreads();

    int w = t >> 6;
    int l15 = t & 15, quad = (t & 63) >> 4;

    f4 acc[2][8];
#pragma unroll
    for (int mt = 0; mt < 2; mt++)
#pragma unroll
        for (int nt = 0; nt < 8; nt++) acc[mt][nt] = (f4){0.f, 0.f, 0.f, 0.f};

#pragma unroll
    for (int ks = 0; ks < 4; ks++) {
        bf8 a[2], b[8];
#pragma unroll
        for (int mt = 0; mt < 2; mt++) {
            int node = w * 32 + mt * 16 + l15;
            int cs = (ks * 4 + quad) ^ (node & 15);
            a[mt] = *(const bf8*)&s5[node * 128 + cs * 8];
        }
#pragma unroll
        for (int nt = 0; nt < 8; nt++) {
            int o = nt * 16 + l15;
            int cs = (ks * 4 + quad) ^ (o & 15);
            b[nt] = *(const bf8*)&s5[16384 + o * 128 + cs * 8];
        }
#pragma unroll
        for (int mt = 0; mt < 2; mt++)
#pragma unroll
            for (int nt = 0; nt < 8; nt++)
                acc[mt][nt] = __builtin_amdgcn_mfma_f32_16x16x32_bf16(
                    a[mt], b[nt], acc[mt][nt], 0, 0, 0);
    }

    float b2v[8];
#pragma unroll
    for (int nt = 0; nt < 8; nt++) b2v[nt] = b2f[nt * 16 + l15];

#pragma unroll
    for (int mt = 0; mt < 2; mt++)
#pragma unroll
        for (int nt = 0; nt < 8; nt++)
#pragma unroll
            for (int r = 0; r < 4; r++) {
                int node = n0 + w * 32 + mt * 16 + quad * 4 + r;
                out[(size_t)node * 128 + nt * 16 + l15] = acc[mt][nt][r] + b2v[nt];
            }
}

extern "C" void kernel_launch(void* const* d_in, const int* in_sizes, int n_in,
                              void* d_out, int out_size, void* d_ws, size_t ws_size,
                              hipStream_t stream) {
    const float* x     = (const float*)d_in[0];
    const int*   ei    = (const int*)d_in[1];
    const float* W1    = (const float*)d_in[2];
    const float* b1    = (const float*)d_in[3];
    const float* u1    = (const float*)d_in[4];
    const float* gamma = (const float*)d_in[5];
    const float* beta  = (const float*)d_in[6];
    const float* W2    = (const float*)d_in[7];
    const float* b2    = (const float*)d_in[8];
    const float* u2    = (const float*)d_in[9];
    float* out = (float*)d_out;

    int N = in_sizes[0] / 64;     // 65536
    int E = in_sizes[1] / 2;      // 1048576
    int nblk = N / 128;           // 512

    char* ws = (char*)d_ws;
    size_t off = 0;
    short* hbf     = (short*)(ws + off); off += (size_t)N * 64 * 2;      // 8 MB
    char*  region2 = ws + off;           off += (size_t)N * 128 * 2;     // 16 MB
    // region2 lifetime: [pairs 5.77MB | xbf 8MB] die after kaggs; then h1bf.
    unsigned* pairs = (unsigned*)region2;
    unsigned short* xbf = (unsigned short*)(region2 + (size_t)NB * CAP * 4);
    short*    h1bf  = (short*)region2;
    int*   gcount  = (int*)(ws + off);   off += 512 * 4;
    float* bnacc   = (float*)(ws + off); off += 256 * 4;   // contiguous w/ gcount
    float* sinv    = (float*)(ws + off); off += 16 * 4;
    float* b2f     = (float*)(ws + off); off += 128 * 4;
    short* w1bf    = (short*)(ws + off); off += 128 * 64 * 2;
    short* w2fbf   = (short*)(ws + off); off += 128 * 128 * 2;

    // prep: x->bf16, W1->bf16, zero gcount+bnacc  (2053 blocks)
    kprep<<<2053, 256, 0, stream>>>(x, (unsigned*)xbf, W1, w1bf, gcount);
    // bin edges into 512 per-bucket packed lists + sigma in spare block
    kbin<<<257, 512, 0, stream>>>(ei, E, gcount, pairs, W1, u1, W2, u2, sinv);
    // per-bucket LDS-CSR + paired register gather: hbf = bf16(x + sum x[src])
    kaggs<<<NB, 512, 0, stream>>>(pairs, gcount, (const unsigned*)xbf,
                                  (unsigned*)hbf);
    // h1 = relu(gemm1) -> bf16 + BN atomic accumulation
    k3_gemm1<<<nblk, 256, 0, stream>>>(hbf, w1bf, b1, sinv, h1bf, bnacc);
    // fold BN + sigma2 into bf16 W2f
    k4_fold<<<1, 128, 0, stream>>>(bnacc, N, gamma, beta, W2, b2, sinv, w2fbf, b2f);
    // out = h1 @ W2f^T + b2f
    k5_gemm2<<<nblk, 256, 0, stream>>>(h1bf, w2fbf, b2f, out);
}

// Round 10
// 163.966 us; speedup vs baseline: 1.2920x; 1.0963x over previous
//
#include <hip/hip_runtime.h>

// N=65536, E=1048576, nfeat=64, nhid=128. Inputs fp32; edge_index int32.
// 3-kernel pipeline:
//  K1: edge binning (512 buckets x 128 nodes) + x->bf16 + W1->bf16 + sigmas
//  K2: per-bucket LDS-CSR + paired register gather + MFMA gemm1 (+BN atomics);
//      h1 tile (bf16) stored in d_out's own 64KB tile slot (first 32KB).
//  K3: per-block BN fold of W2 (exact fp32 accb) + MFMA gemm2, in-place on d_out.

#define BN_EPS 1e-5f
#define NB   512      // buckets (128 nodes each)
#define CAP  2816     // per-bucket capacity (avg 2048, +17 sigma; mult of 4)

typedef float f4 __attribute__((ext_vector_type(4)));
typedef short bf8 __attribute__((ext_vector_type(8)));   // 8 bf16 = 4 VGPRs

__device__ inline short f2bf(float f) {
    unsigned u = __float_as_uint(f);
    u = u + 0x7fffu + ((u >> 16) & 1u);   // round-to-nearest-even
    return (short)(u >> 16);
}
__device__ inline float bf2f(unsigned short u) {
    return __uint_as_float((unsigned)u << 16);
}
__device__ inline unsigned pk2(float a, float b) {
    return (unsigned)(unsigned short)f2bf(a) |
           ((unsigned)(unsigned short)f2bf(b) << 16);
}

// ================= K1: binning + casts + sigma =================
// blocks 0..255: bin 4096 edges each. Packed: [31:23]=bucket [22:7]=src [6:0]=dst&127
// blocks 256..511: x->bf16 (each thread 4 uint4)
// block 512: W1->bf16 + spectral-norm sigmas
__global__ __launch_bounds__(512) void k1_bin(const int* __restrict__ ei, int E,
                                              int* __restrict__ gcount,
                                              unsigned* __restrict__ pairs,
                                              const float* __restrict__ x,
                                              unsigned* __restrict__ xbf2,
                                              const float* __restrict__ W1,
                                              short* __restrict__ w1bf,
                                              const float* __restrict__ u1,
                                              const float* __restrict__ W2,
                                              const float* __restrict__ u2,
                                              float* __restrict__ sinv) {
    __shared__ int hist[512];
    __shared__ int sbase[512];
    __shared__ int cur[512];
    __shared__ int gofs[512];
    __shared__ unsigned stage[4096];
    int t = threadIdx.x;
    int bid = blockIdx.x;

    if (bid < 256) {
        hist[t] = 0;
        __syncthreads();

        const uint4* s4 = (const uint4*)ei + bid * 1024;
        const uint4* d4 = (const uint4*)(ei + E) + bid * 1024;
        unsigned pk[8];
#pragma unroll
        for (int i = 0; i < 2; i++) {
            int idx = i * 512 + t;
            uint4 sv = s4[idx];
            uint4 dv = d4[idx];
            pk[i * 4 + 0] = ((dv.x >> 7) << 23) | (sv.x << 7) | (dv.x & 127u);
            pk[i * 4 + 1] = ((dv.y >> 7) << 23) | (sv.y << 7) | (dv.y & 127u);
            pk[i * 4 + 2] = ((dv.z >> 7) << 23) | (sv.z << 7) | (dv.z & 127u);
            pk[i * 4 + 3] = ((dv.w >> 7) << 23) | (sv.w << 7) | (dv.w & 127u);
            atomicAdd(&hist[dv.x >> 7], 1);
            atomicAdd(&hist[dv.y >> 7], 1);
            atomicAdd(&hist[dv.z >> 7], 1);
            atomicAdd(&hist[dv.w >> 7], 1);
        }
        __syncthreads();

        int cntb = hist[t];
        for (int o = 1; o < 512; o <<= 1) {
            int v = (t >= o) ? hist[t - o] : 0;
            __syncthreads();
            hist[t] += v;
            __syncthreads();
        }
        int excl = hist[t] - cntb;
        sbase[t] = excl;
        cur[t] = excl;
        __syncthreads();

#pragma unroll
        for (int i = 0; i < 8; i++) {
            int p = atomicAdd(&cur[pk[i] >> 23], 1);
            stage[p] = pk[i];
        }
        __syncthreads();

        gofs[t] = atomicAdd(&gcount[t], cntb);
        __syncthreads();

#pragma unroll
        for (int i = 0; i < 8; i++) {
            int p = i * 512 + t;
            unsigned v = stage[p];
            int b = (int)(v >> 23);
            int li = p - sbase[b];
            pairs[(size_t)b * CAP + gofs[b] + li] = v & 0x7FFFFFu;
        }
    } else if (bid < 512) {
        // x cast: 256 blocks x 512 thr x 4 uint4 = 524288 uint4 = N*8
        int cb = bid - 256;
        const float4* xp = (const float4*)x;
#pragma unroll
        for (int k = 0; k < 4; k++) {
            int i = cb * 2048 + k * 512 + t;
            float4 a = xp[2 * i], b = xp[2 * i + 1];
            uint4 o = {pk2(a.x, a.y), pk2(a.z, a.w), pk2(b.x, b.y), pk2(b.z, b.w)};
            ((uint4*)xbf2)[i] = o;
        }
    } else {
        // W1 cast: 8192 elems
#pragma unroll
        for (int k = 0; k < 2; k++) {
            int idx = k * 512 + t;           // uint4 index (1024 total)
            const float4* wp = (const float4*)W1;
            float4 a = wp[2 * idx], b = wp[2 * idx + 1];
            uint4 o = {pk2(a.x, a.y), pk2(a.z, a.w), pk2(b.x, b.y), pk2(b.z, b.w)};
            ((uint4*)w1bf)[idx] = o;
        }
        // ---- sigmas (LDS-tree, no shuffle chains) ----
        float* red = (float*)stage;     // 512 floats
        float* v   = (float*)hist;      // 128 floats
        float* sq  = (float*)sbase;     // 512 floats scratch

        // === W1 (128x64) ===
        {
            int j = t & 63, q = t >> 6;
            float s = 0.f;
            for (int i = q * 16; i < q * 16 + 16; i++) s += W1[i * 64 + j] * u1[i];
            red[t] = s;
        }
        __syncthreads();
        if (t < 64) {
            float vj = 0.f;
#pragma unroll
            for (int g = 0; g < 8; g++) vj += red[g * 64 + t];
            v[t] = vj; sq[t] = vj * vj;
        }
        __syncthreads();
        for (int s2 = 32; s2 > 0; s2 >>= 1) {
            if (t < s2) sq[t] += sq[t + s2];
            __syncthreads();
        }
        if (t < 64) v[t] = v[t] / (sqrtf(sq[0]) + 1e-12f);
        __syncthreads();
        {
            int r = t >> 2, h = t & 3;
            const float4* wr = (const float4*)(W1 + r * 64 + h * 16);
            const float4* vv = (const float4*)v + h * 4;
            float s = 0.f;
#pragma unroll
            for (int k = 0; k < 4; k++) {
                float4 a = wr[k]; float4 b = vv[k];
                s += a.x * b.x + a.y * b.y + a.z * b.z + a.w * b.w;
            }
            red[t] = s;
        }
        __syncthreads();
        if (t < 128) {
            float tr = (red[4 * t] + red[4 * t + 1]) + (red[4 * t + 2] + red[4 * t + 3]);
            sq[t] = tr * tr;
        }
        __syncthreads();
        for (int s2 = 64; s2 > 0; s2 >>= 1) {
            if (t < s2) sq[t] += sq[t + s2];
            __syncthreads();
        }
        if (t == 0) { float nt2 = sq[0]; sinv[0] = (sqrtf(nt2) + 1e-12f) / nt2; }
        __syncthreads();

        // === W2 (128x128) ===
        {
            int j = t & 127, q = t >> 7;
            float s = 0.f;
            for (int i = q * 32; i < q * 32 + 32; i++) s += W2[i * 128 + j] * u2[i];
            red[t] = s;
        }
        __syncthreads();
        if (t < 128) {
            float vj = (red[t] + red[128 + t]) + (red[256 + t] + red[384 + t]);
            v[t] = vj; sq[t] = vj * vj;
        }
        __syncthreads();
        for (int s2 = 64; s2 > 0; s2 >>= 1) {
            if (t < s2) sq[t] += sq[t + s2];
            __syncthreads();
        }
        if (t < 128) v[t] = v[t] / (sqrtf(sq[0]) + 1e-12f);
        __syncthreads();
        {
            int r = t >> 2, h = t & 3;
            const float4* wr = (const float4*)(W2 + r * 128 + h * 32);
            const float4* vv = (const float4*)v + h * 8;
            float s = 0.f;
#pragma unroll
            for (int k = 0; k < 8; k++) {
                float4 a = wr[k]; float4 b = vv[k];
                s += a.x * b.x + a.y * b.y + a.z * b.z + a.w * b.w;
            }
            red[t] = s;
        }
        __syncthreads();
        if (t < 128) {
            float tr = (red[4 * t] + red[4 * t + 1]) + (red[4 * t + 2] + red[4 * t + 3]);
            sq[t] = tr * tr;
        }
        __syncthreads();
        for (int s2 = 64; s2 > 0; s2 >>= 1) {
            if (t < s2) sq[t] += sq[t + s2];
            __syncthreads();
        }
        if (t == 0) { float nt2 = sq[0]; sinv[1] = (sqrtf(nt2) + 1e-12f) / nt2; }
    }
}

// ================= K2: aggregate + gemm1 fused =================
// One 512-thread block (8 waves) per bucket of 128 nodes.
// Phases: LDS-CSR build -> paired register gather (h in regs) ->
// h+W1 tiles in LDS -> MFMA (wave = 16 nodes x 128 outs) -> relu/scale ->
// BN col sums (atomics to bnacc) -> h1 bf16 tile into d_out slot b (first 32KB).
__global__ __launch_bounds__(512) void k2_agg_gemm1(
        const unsigned* __restrict__ pairs,
        const int* __restrict__ gcount,
        const unsigned* __restrict__ xbf2,
        const short* __restrict__ w1bf,
        const float* __restrict__ b1,
        const float* __restrict__ sinv,
        char* __restrict__ outbase,          // d_out as bytes
        float* __restrict__ bnacc) {
    __shared__ short u[16384];              // 32 KB multi-use
    __shared__ unsigned short sorted[CAP];  // 5.5 KB
    __shared__ int hist[128];
    __shared__ int offs[128];
    __shared__ int cur[128];
    __shared__ float red1[1024], red2[1024];
    int t = threadIdx.x;
    int b = blockIdx.x;
    int cnt = gcount[b];

    // ---- CSR build (ep staged in u's first 11 KB) ----
    unsigned* ep = (unsigned*)u;
    {
        const uint4* gp4 = (const uint4*)(pairs + (size_t)b * CAP);
        int cnt4 = (cnt + 3) >> 2;
        for (int j = t; j < cnt4; j += 512) ((uint4*)ep)[j] = gp4[j];
    }
    if (t < 128) hist[t] = 0;
    __syncthreads();
    for (int j = t; j < cnt; j += 512) atomicAdd(&hist[ep[j] & 127u], 1);
    __syncthreads();
    int cntb = (t < 128) ? hist[t] : 0;
    for (int o = 1; o < 128; o <<= 1) {
        int v = (t < 128 && t >= o) ? hist[t - o] : 0;
        __syncthreads();
        if (t < 128) hist[t] += v;
        __syncthreads();
    }
    if (t < 128) { offs[t] = hist[t] - cntb; cur[t] = hist[t] - cntb; }
    __syncthreads();
    for (int j = t; j < cnt; j += 512) {
        unsigned v = ep[j];
        int p = atomicAdd(&cur[v & 127u], 1);
        sorted[p] = (unsigned short)(v >> 7);
    }
    __syncthreads();   // ep dead from here

    // ---- paired register gather ----
    int w = t >> 6;
    int lane = t & 63;
    int h = lane >> 5;        // edge parity
    int l = lane & 31;        // feature pair (2l, 2l+1)
    float hr0[16], hr1[16];

#pragma unroll
    for (int ni = 0; ni < 16; ni++) {
        int n = w * 16 + ni;
        int g = b * 128 + n;
        int beg = offs[n], end = hist[n];
        float a0 = 0.f, a1 = 0.f, b0 = 0.f, b1r = 0.f;
        float c0 = 0.f, c1 = 0.f, d0 = 0.f, d1 = 0.f;
        int j = beg + h;
        for (; j + 6 < end; j += 8) {
            int s0 = sorted[j];
            int s1 = sorted[j + 2];
            int s2 = sorted[j + 4];
            int s3 = sorted[j + 6];
            unsigned v0 = xbf2[(size_t)s0 * 32 + l];
            unsigned v1 = xbf2[(size_t)s1 * 32 + l];
            unsigned v2 = xbf2[(size_t)s2 * 32 + l];
            unsigned v3 = xbf2[(size_t)s3 * 32 + l];
            a0 += bf2f((unsigned short)v0); a1 += bf2f((unsigned short)(v0 >> 16));
            b0 += bf2f((unsigned short)v1); b1r += bf2f((unsigned short)(v1 >> 16));
            c0 += bf2f((unsigned short)v2); c1 += bf2f((unsigned short)(v2 >> 16));
            d0 += bf2f((unsigned short)v3); d1 += bf2f((unsigned short)(v3 >> 16));
        }
        for (; j < end; j += 2) {
            unsigned v = xbf2[(size_t)sorted[j] * 32 + l];
            a0 += bf2f((unsigned short)v); a1 += bf2f((unsigned short)(v >> 16));
        }
        a0 = (a0 + b0) + (c0 + d0);
        a1 = (a1 + b1r) + (c1 + d1);
        a0 += __shfl_xor(a0, 32);
        a1 += __shfl_xor(a1, 32);
        unsigned xs = xbf2[(size_t)g * 32 + l];
        a0 += bf2f((unsigned short)xs);
        a1 += bf2f((unsigned short)(xs >> 16));
        hr0[ni] = a0; hr1[ni] = a1;       // valid on h==0 lanes
    }
    __syncthreads();   // all gathers done; u free for h-tile

    // ---- write h tile (bf16, 8-chunk swizzle) + stage W1 ----
    if (h == 0) {
#pragma unroll
        for (int ni = 0; ni < 16; ni++) {
            int n = w * 16 + ni;
            int c = l >> 2;
            int cs = c ^ (n & 7);
            *(unsigned*)&u[n * 64 + cs * 8 + (l & 3) * 2] = pk2(hr0[ni], hr1[ni]);
        }
    }
    {
        const bf8* wsrc = (const bf8*)w1bf;
#pragma unroll
        for (int i = 0; i < 2; i++) {
            int idx = i * 512 + t;           // 1024 bf8
            int row = idx >> 3, c = idx & 7;
            int cs = c ^ (row & 7);
            *(bf8*)&u[8192 + row * 64 + cs * 8] = wsrc[idx];
        }
    }
    __syncthreads();

    // ---- MFMA: wave w handles nodes w*16..+15, all 128 outs ----
    int l15 = lane & 15, quad = lane >> 4;
    f4 acc[8];
#pragma unroll
    for (int nt = 0; nt < 8; nt++) acc[nt] = (f4){0.f, 0.f, 0.f, 0.f};

#pragma unroll
    for (int ks = 0; ks < 2; ks++) {
        bf8 a, bfr[8];
        {
            int node = w * 16 + l15;
            int cs = (ks * 4 + quad) ^ (node & 7);
            a = *(const bf8*)&u[node * 64 + cs * 8];
        }
#pragma unroll
        for (int nt = 0; nt < 8; nt++) {
            int o = nt * 16 + l15;
            int cs = (ks * 4 + quad) ^ (o & 7);
            bfr[nt] = *(const bf8*)&u[8192 + o * 64 + cs * 8];
        }
#pragma unroll
        for (int nt = 0; nt < 8; nt++)
            acc[nt] = __builtin_amdgcn_mfma_f32_16x16x32_bf16(a, bfr[nt], acc[nt], 0, 0, 0);
    }

    // ---- epilogue: relu(s1*acc+b1), BN col sums ----
    float s1 = sinv[0];
#pragma unroll
    for (int nt = 0; nt < 8; nt++) {
        float bb = b1[nt * 16 + l15];
        float s = 0.f, q = 0.f;
#pragma unroll
        for (int r = 0; r < 4; r++) {
            float v = fmaxf(fmaf(acc[nt][r], s1, bb), 0.f);
            acc[nt][r] = v;
            s += v; q += v * v;
        }
        s += __shfl_xor(s, 16); s += __shfl_xor(s, 32);
        q += __shfl_xor(q, 16); q += __shfl_xor(q, 32);
        if (quad == 0) {
            red1[w * 128 + nt * 16 + l15] = s;
            red2[w * 128 + nt * 16 + l15] = q;
        }
    }
    __syncthreads();   // fragments consumed; reuse u as h1 tile (128x128 bf16)

#pragma unroll
    for (int nt = 0; nt < 8; nt++) {
        int col = nt * 16 + l15;
#pragma unroll
        for (int r = 0; r < 4; r++) {
            int row = w * 16 + quad * 4 + r;
            int cs = (col >> 3) ^ (row & 15);
            u[row * 128 + cs * 8 + (col & 7)] = f2bf(acc[nt][r]);
        }
    }
    __syncthreads();

    // ---- h1 tile -> d_out slot b (first 32 KB of its 64 KB region) ----
    bf8* dst = (bf8*)(outbase + (size_t)b * 65536);
#pragma unroll
    for (int i = 0; i < 4; i++) {
        int idx = i * 512 + t;              // 2048 bf8
        int row = idx >> 4, c = idx & 15;
        int cs = c ^ (row & 15);
        dst[idx] = *(const bf8*)&u[row * 128 + cs * 8];
    }
    // BN atomics
    if (t < 128) {
        float s = 0.f, q = 0.f;
#pragma unroll
        for (int g = 0; g < 8; g++) { s += red1[g * 128 + t]; q += red2[g * 128 + t]; }
        atomicAdd(&bnacc[t], s);
        atomicAdd(&bnacc[128 + t], q);
    }
}

// ================= K3: BN fold + gemm2 fused =================
// 512 blocks x 256 threads. Each block: fold W2 (redundant, cheap) into LDS
// bf16, stage its h1 tile from d_out slot, MFMA, overwrite slot with fp32 out.
__global__ __launch_bounds__(256) void k3_fold_gemm2(
        const float* __restrict__ bnacc, int N,
        const float* __restrict__ gamma,
        const float* __restrict__ beta,
        const float* __restrict__ W2,
        const float* __restrict__ b2,
        const float* __restrict__ sinv,
        char* __restrict__ outbase) {
    __shared__ short s5[32768];   // [0..16383]=h1 tile, [16384..]=w2s; 64 KB
    float* fs = (float*)s5;       // transient: a_s[0..127], c_s[128..255], b2f[256..383]
    int t = threadIdx.x;
    int b = blockIdx.x;

    if (t < 128) {
        float mean = bnacc[t] / (float)N;
        float var = bnacc[t + 128] / (float)N - mean * mean;
        float rstd = rsqrtf(var + BN_EPS);
        float a = rstd * gamma[t];
        fs[t] = a;
        fs[128 + t] = beta[t] - mean * a;
    }
    __syncthreads();

    // stage folded W2 (bf16, 16-chunk swizzle): thread -> row o=t>>1, 64 cols
    float s2 = sinv[1];
    {
        int o = t >> 1;
        int jbase = (t & 1) * 64;
        const float4* wr = (const float4*)(W2 + o * 128 + jbase);
#pragma unroll
        for (int k = 0; k < 8; k++) {
            int c = (jbase >> 3) + k;
            float4 a = wr[2 * k], bb = wr[2 * k + 1];
            int j0 = jbase + k * 8;
            bf8 v;
            v[0] = f2bf(a.x * s2 * fs[j0 + 0]);
            v[1] = f2bf(a.y * s2 * fs[j0 + 1]);
            v[2] = f2bf(a.z * s2 * fs[j0 + 2]);
            v[3] = f2bf(a.w * s2 * fs[j0 + 3]);
            v[4] = f2bf(bb.x * s2 * fs[j0 + 4]);
            v[5] = f2bf(bb.y * s2 * fs[j0 + 5]);
            v[6] = f2bf(bb.z * s2 * fs[j0 + 6]);
            v[7] = f2bf(bb.w * s2 * fs[j0 + 7]);
            int cs = c ^ (o & 15);
            *(bf8*)&s5[16384 + o * 128 + cs * 8] = v;
        }
    }
    // exact fp32 b2f
    if (t < 128) {
        float accb = 0.f;
        for (int j = 0; j < 128; j++)
            accb += W2[t * 128 + j] * s2 * fs[128 + j];
        fs[256 + t] = b2[t] + accb;
    }
    __syncthreads();

    int w = t >> 6;
    int lane = t & 63;
    int l15 = lane & 15, quad = lane >> 4;
    float b2v[8];
#pragma unroll
    for (int nt = 0; nt < 8; nt++) b2v[nt] = fs[256 + nt * 16 + l15];
    __syncthreads();   // b2v read; fs region free for h1 tile

    // stage h1 tile from d_out slot b
    {
        const bf8* hsrc = (const bf8*)(outbase + (size_t)b * 65536);
#pragma unroll
        for (int i = 0; i < 8; i++) {
            int idx = i * 256 + t;          // 2048 bf8
            int row = idx >> 4, c = idx & 15;
            int cs = c ^ (row & 15);
            *(bf8*)&s5[row * 128 + cs * 8] = hsrc[idx];
        }
    }
    __syncthreads();

    f4 acc[2][8];
#pragma unroll
    for (int mt = 0; mt < 2; mt++)
#pragma unroll
        for (int nt = 0; nt < 8; nt++) acc[mt][nt] = (f4){0.f, 0.f, 0.f, 0.f};

#pragma unroll
    for (int ks = 0; ks < 4; ks++) {
        bf8 a[2], bfr[8];
#pragma unroll
        for (int mt = 0; mt < 2; mt++) {
            int node = w * 32 + mt * 16 + l15;
            int cs = (ks * 4 + quad) ^ (node & 15);
            a[mt] = *(const bf8*)&s5[node * 128 + cs * 8];
        }
#pragma unroll
        for (int nt = 0; nt < 8; nt++) {
            int o = nt * 16 + l15;
            int cs = (ks * 4 + quad) ^ (o & 15);
            bfr[nt] = *(const bf8*)&s5[16384 + o * 128 + cs * 8];
        }
#pragma unroll
        for (int mt = 0; mt < 2; mt++)
#pragma unroll
            for (int nt = 0; nt < 8; nt++)
                acc[mt][nt] = __builtin_amdgcn_mfma_f32_16x16x32_bf16(
                    a[mt], bfr[nt], acc[mt][nt], 0, 0, 0);
    }

    float* out = (float*)(outbase + (size_t)b * 65536);
#pragma unroll
    for (int mt = 0; mt < 2; mt++)
#pragma unroll
        for (int nt = 0; nt < 8; nt++)
#pragma unroll
            for (int r = 0; r < 4; r++) {
                int row = w * 32 + mt * 16 + quad * 4 + r;   // local node
                out[(size_t)row * 128 + nt * 16 + l15] = acc[mt][nt][r] + b2v[nt];
            }
}

extern "C" void kernel_launch(void* const* d_in, const int* in_sizes, int n_in,
                              void* d_out, int out_size, void* d_ws, size_t ws_size,
                              hipStream_t stream) {
    const float* x     = (const float*)d_in[0];
    const int*   ei    = (const int*)d_in[1];
    const float* W1    = (const float*)d_in[2];
    const float* b1    = (const float*)d_in[3];
    const float* u1    = (const float*)d_in[4];
    const float* gamma = (const float*)d_in[5];
    const float* beta  = (const float*)d_in[6];
    const float* W2    = (const float*)d_in[7];
    const float* b2    = (const float*)d_in[8];
    const float* u2    = (const float*)d_in[9];

    int N = in_sizes[0] / 64;     // 65536
    int E = in_sizes[1] / 2;      // 1048576

    char* ws = (char*)d_ws;
    size_t off = 0;
    unsigned* pairs = (unsigned*)(ws + off); off += (size_t)NB * CAP * 4;  // 5.77 MB
    unsigned short* xbf = (unsigned short*)(ws + off); off += (size_t)N * 64 * 2; // 8 MB
    int*   gcount  = (int*)(ws + off);   off += 512 * 4;
    float* bnacc   = (float*)(ws + off); off += 256 * 4;   // contiguous w/ gcount
    float* sinv    = (float*)(ws + off); off += 16 * 4;
    short* w1bf    = (short*)(ws + off); off += 128 * 64 * 2;

    // zero gcount(512 int) + bnacc(256 float) in one memset (contiguous)
    hipMemsetAsync(gcount, 0, 512 * 4 + 256 * 4, stream);
    // K1: binning + x/W1 casts + sigmas
    k1_bin<<<513, 512, 0, stream>>>(ei, E, gcount, pairs, x, (unsigned*)xbf,
                                    W1, w1bf, u1, W2, u2, sinv);
    // K2: aggregate + gemm1 -> h1 bf16 tiles into d_out slots + BN atomics
    k2_agg_gemm1<<<NB, 512, 0, stream>>>(pairs, gcount, (const unsigned*)xbf,
                                         w1bf, b1, sinv, (char*)d_out, bnacc);
    // K3: BN fold + gemm2, in place on d_out
    k3_fold_gemm2<<<NB, 256, 0, stream>>>(bnacc, N, gamma, beta, W2, b2, sinv,
                                          (char*)d_out);
}